// Round 1
// baseline (309.687 us; speedup 1.0000x reference)
//
#include <hip/hip_runtime.h>
#include <hip/hip_bf16.h>

#define N 8192
#define M 8192
#define D 64

typedef __bf16 bf16x8 __attribute__((ext_vector_type(8)));
typedef float f32x4 __attribute__((ext_vector_type(4)));

// ---------------------------------------------------------------------------
// Prep: split fp32 rows into bf16 hi/lo and compute fp32 row norms.
// One 64-lane wave per row (D=64 -> one element per lane). 4 rows per block.
// ---------------------------------------------------------------------------
__global__ __launch_bounds__(256) void prep_kernel(
    const float* __restrict__ x, const float* __restrict__ y,
    __bf16* __restrict__ xh, __bf16* __restrict__ xl, float* __restrict__ xn,
    __bf16* __restrict__ yh, __bf16* __restrict__ yl, float* __restrict__ yn)
{
    int row  = blockIdx.x * 4 + (threadIdx.x >> 6);
    int lane = threadIdx.x & 63;

    const float* src;
    __bf16 *h, *l;
    float* nrm;
    int r;
    if (row < N) { src = x; h = xh; l = xl; nrm = xn; r = row; }
    else         { src = y; h = yh; l = yl; nrm = yn; r = row - N; }

    float v = src[(size_t)r * D + lane];
    __bf16 hi = (__bf16)v;                 // RNE round to bf16
    float  lof = v - (float)hi;            // exact residual in fp32
    __bf16 lo = (__bf16)lof;

    h[(size_t)r * D + lane] = hi;
    l[(size_t)r * D + lane] = lo;

    float s = v * v;
    #pragma unroll
    for (int off = 32; off; off >>= 1) s += __shfl_down(s, off, 64);
    if (lane == 0) nrm[r] = s;
}

// ---------------------------------------------------------------------------
// Main: each 256-thread block computes a 128x128 output tile; each wave a
// 64x64 sub-tile via 16x16x32 bf16 MFMA, bf16x3 split precision
// (xh*yh + xh*yl + xl*yh accumulated in fp32).
// A-frag: lane holds A[m=lane&15][k=quad*8 + j]  (8 contiguous bf16 = 16B)
// B-frag: lane holds B[k=quad*8 + j][n=lane&15]  -> y row-major, same pattern
// C/D:    col = lane&15, row = quad*4 + reg      (verified m89/m91)
// ---------------------------------------------------------------------------
__global__ __launch_bounds__(256) void rbf_kernel(
    const __bf16* __restrict__ xh, const __bf16* __restrict__ xl,
    const float* __restrict__ xn,
    const __bf16* __restrict__ yh, const __bf16* __restrict__ yl,
    const float* __restrict__ yn,
    const float* __restrict__ sig, float* __restrict__ out)
{
    int tid  = threadIdx.x;
    int wave = tid >> 6;
    int lane = tid & 63;
    int quad = lane >> 4;
    int l16  = lane & 15;

    int i_base = blockIdx.y * 128 + (wave >> 1) * 64;
    int j_base = blockIdx.x * 128 + (wave & 1) * 64;

    float s = sig[0];
    float scale = -0.5f / (s * s);

    // Load A fragments for this wave's 64 rows (held across the j loop).
    bf16x8 Ah[4][2], Al[4][2];
    #pragma unroll
    for (int ti = 0; ti < 4; ++ti) {
        int row = i_base + ti * 16 + l16;
        #pragma unroll
        for (int k = 0; k < 2; ++k) {
            int off = row * D + k * 32 + quad * 8;   // element offset, 16B aligned
            Ah[ti][k] = *reinterpret_cast<const bf16x8*>(xh + off);
            Al[ti][k] = *reinterpret_cast<const bf16x8*>(xl + off);
        }
    }

    // x-norms for the rows this lane's accumulator registers map to.
    float xnr[4][4];
    #pragma unroll
    for (int ti = 0; ti < 4; ++ti)
        #pragma unroll
        for (int r = 0; r < 4; ++r)
            xnr[ti][r] = xn[i_base + ti * 16 + quad * 4 + r];

    #pragma unroll
    for (int tj = 0; tj < 4; ++tj) {
        int col = j_base + tj * 16 + l16;

        bf16x8 Bh[2], Bl[2];
        #pragma unroll
        for (int k = 0; k < 2; ++k) {
            int off = col * D + k * 32 + quad * 8;
            Bh[k] = *reinterpret_cast<const bf16x8*>(yh + off);
            Bl[k] = *reinterpret_cast<const bf16x8*>(yl + off);
        }
        float ynj = yn[col];

        f32x4 acc[4];
        #pragma unroll
        for (int ti = 0; ti < 4; ++ti) acc[ti] = (f32x4){0.f, 0.f, 0.f, 0.f};

        #pragma unroll
        for (int ti = 0; ti < 4; ++ti) {
            #pragma unroll
            for (int k = 0; k < 2; ++k) {
                acc[ti] = __builtin_amdgcn_mfma_f32_16x16x32_bf16(Ah[ti][k], Bh[k], acc[ti], 0, 0, 0);
                acc[ti] = __builtin_amdgcn_mfma_f32_16x16x32_bf16(Ah[ti][k], Bl[k], acc[ti], 0, 0, 0);
                acc[ti] = __builtin_amdgcn_mfma_f32_16x16x32_bf16(Al[ti][k], Bh[k], acc[ti], 0, 0, 0);
            }
        }

        // Epilogue: sqd = |x|^2 + |y|^2 - 2 x.y, clamp, exp.
        #pragma unroll
        for (int ti = 0; ti < 4; ++ti) {
            #pragma unroll
            for (int r = 0; r < 4; ++r) {
                int row = i_base + ti * 16 + quad * 4 + r;
                float sqd = xnr[ti][r] + ynj - 2.0f * acc[ti][r];
                sqd = fmaxf(sqd, 0.0f);
                out[(size_t)row * M + col] = __expf(scale * sqd);
            }
        }
    }
}

extern "C" void kernel_launch(void* const* d_in, const int* in_sizes, int n_in,
                              void* d_out, int out_size, void* d_ws, size_t ws_size,
                              hipStream_t stream) {
    const float* x   = (const float*)d_in[0];
    const float* y   = (const float*)d_in[1];
    const float* sig = (const float*)d_in[2];
    float* out = (float*)d_out;

    char* ws = (char*)d_ws;
    __bf16* xh = (__bf16*)(ws);
    __bf16* xl = (__bf16*)(ws + (1u << 20));
    __bf16* yh = (__bf16*)(ws + (2u << 20));
    __bf16* yl = (__bf16*)(ws + (3u << 20));
    float*  xn = (float*) (ws + (4u << 20));
    float*  yn = (float*) (ws + (4u << 20) + (1u << 15));

    prep_kernel<<<(N + M) / 4, 256, 0, stream>>>(x, y, xh, xl, xn, yh, yl, yn);

    dim3 grid(M / 128, N / 128);
    rbf_kernel<<<grid, 256, 0, stream>>>(xh, xl, xn, yh, yl, yn, sig, out);
}

// Round 2
// 291.188 us; speedup vs baseline: 1.0635x; 1.0635x over previous
//
#include <hip/hip_runtime.h>
#include <hip/hip_bf16.h>

#define N 8192
#define M 8192
#define D 64

typedef __bf16 bf16x8 __attribute__((ext_vector_type(8)));
typedef float f32x4 __attribute__((ext_vector_type(4)));

// ---------------------------------------------------------------------------
// Prep: split fp32 rows into bf16 hi/lo and compute fp32 row norms.
// One 64-lane wave per row (D=64 -> one element per lane). 4 rows per block.
// ---------------------------------------------------------------------------
__global__ __launch_bounds__(256) void prep_kernel(
    const float* __restrict__ x, const float* __restrict__ y,
    __bf16* __restrict__ xh, __bf16* __restrict__ xl, float* __restrict__ xn,
    __bf16* __restrict__ yh, __bf16* __restrict__ yl, float* __restrict__ yn)
{
    int row  = blockIdx.x * 4 + (threadIdx.x >> 6);
    int lane = threadIdx.x & 63;

    const float* src;
    __bf16 *h, *l;
    float* nrm;
    int r;
    if (row < N) { src = x; h = xh; l = xl; nrm = xn; r = row; }
    else         { src = y; h = yh; l = yl; nrm = yn; r = row - N; }

    float v = src[(size_t)r * D + lane];
    __bf16 hi = (__bf16)v;                 // RNE round to bf16
    float  lof = v - (float)hi;            // exact residual in fp32
    __bf16 lo = (__bf16)lof;

    h[(size_t)r * D + lane] = hi;
    l[(size_t)r * D + lane] = lo;

    float s = v * v;
    #pragma unroll
    for (int off = 32; off; off >>= 1) s += __shfl_down(s, off, 64);
    if (lane == 0) nrm[r] = s;
}

// ---------------------------------------------------------------------------
// Main: 128x128 tile per 256-thread block; 64x64 per wave.
// bf16x3 split precision via 16x16x32 MFMA (xh*yh + xh*yl + xl*yh).
//
// Store-coalescing trick: B-fragment iteration t is loaded with global
// columns  col(t, n) = j_base + 4*n + t  (n = lane&15).  Then lane l16's
// accumulator register t holds column j_base + 4*l16 + t, so the four
// t-accumulators form a contiguous f32x4 -> one global_store_dwordx4 per
// (ti, r):  16 fully-coalesced 1 KB store instructions per wave instead of
// 64 scalar stores with 64 B segments.
//
// A-frag: lane holds A[m=lane&15][k=quad*8+j]  (8 contiguous bf16 = 16 B)
// B-frag: lane holds B[k=quad*8+j][n=lane&15]
// C/D:    n = lane&15, m = quad*4 + reg        (verified m89/m91)
// ---------------------------------------------------------------------------
__global__ __launch_bounds__(256) void rbf_kernel(
    const __bf16* __restrict__ xh, const __bf16* __restrict__ xl,
    const float* __restrict__ xn,
    const __bf16* __restrict__ yh, const __bf16* __restrict__ yl,
    const float* __restrict__ yn,
    const float* __restrict__ sig, float* __restrict__ out)
{
    int tid  = threadIdx.x;
    int wave = tid >> 6;
    int lane = tid & 63;
    int quad = lane >> 4;
    int l16  = lane & 15;

    int i_base = blockIdx.y * 128 + (wave >> 1) * 64;
    int j_base = blockIdx.x * 128 + (wave & 1) * 64;

    float s = sig[0];
    float scale = -0.5f / (s * s);

    // B fragments for this wave's 64 columns, permuted: iteration t holds
    // column j_base + 4*l16 + t. Resident across the whole ti loop (64 VGPRs).
    bf16x8 Bh[4][2], Bl[4][2];
    float ynr[4];
    #pragma unroll
    for (int t = 0; t < 4; ++t) {
        int col = j_base + 4 * l16 + t;
        ynr[t] = yn[col];
        #pragma unroll
        for (int k = 0; k < 2; ++k) {
            int off = col * D + k * 32 + quad * 8;   // element offset, 16B aligned
            Bh[t][k] = *reinterpret_cast<const bf16x8*>(yh + off);
            Bl[t][k] = *reinterpret_cast<const bf16x8*>(yl + off);
        }
    }

    #pragma unroll
    for (int ti = 0; ti < 4; ++ti) {
        int arow = i_base + ti * 16 + l16;
        bf16x8 Ah[2], Al[2];
        #pragma unroll
        for (int k = 0; k < 2; ++k) {
            int off = arow * D + k * 32 + quad * 8;
            Ah[k] = *reinterpret_cast<const bf16x8*>(xh + off);
            Al[k] = *reinterpret_cast<const bf16x8*>(xl + off);
        }

        float xnr[4];
        #pragma unroll
        for (int r = 0; r < 4; ++r)
            xnr[r] = xn[i_base + ti * 16 + quad * 4 + r];

        f32x4 acc[4];
        #pragma unroll
        for (int t = 0; t < 4; ++t) acc[t] = (f32x4){0.f, 0.f, 0.f, 0.f};

        #pragma unroll
        for (int t = 0; t < 4; ++t) {
            #pragma unroll
            for (int k = 0; k < 2; ++k) {
                acc[t] = __builtin_amdgcn_mfma_f32_16x16x32_bf16(Ah[k], Bh[t][k], acc[t], 0, 0, 0);
                acc[t] = __builtin_amdgcn_mfma_f32_16x16x32_bf16(Ah[k], Bl[t][k], acc[t], 0, 0, 0);
                acc[t] = __builtin_amdgcn_mfma_f32_16x16x32_bf16(Al[k], Bh[t][k], acc[t], 0, 0, 0);
            }
        }

        // Epilogue: one dwordx4 per (r) — contiguous cols 4*l16 .. 4*l16+3.
        #pragma unroll
        for (int r = 0; r < 4; ++r) {
            int row = i_base + ti * 16 + quad * 4 + r;
            f32x4 v;
            #pragma unroll
            for (int t = 0; t < 4; ++t) {
                float sqd = xnr[r] + ynr[t] - 2.0f * acc[t][r];
                sqd = fmaxf(sqd, 0.0f);
                v[t] = __expf(scale * sqd);
            }
            *reinterpret_cast<f32x4*>(out + (size_t)row * M + j_base + 4 * l16) = v;
        }
    }
}

extern "C" void kernel_launch(void* const* d_in, const int* in_sizes, int n_in,
                              void* d_out, int out_size, void* d_ws, size_t ws_size,
                              hipStream_t stream) {
    const float* x   = (const float*)d_in[0];
    const float* y   = (const float*)d_in[1];
    const float* sig = (const float*)d_in[2];
    float* out = (float*)d_out;

    char* ws = (char*)d_ws;
    __bf16* xh = (__bf16*)(ws);
    __bf16* xl = (__bf16*)(ws + (1u << 20));
    __bf16* yh = (__bf16*)(ws + (2u << 20));
    __bf16* yl = (__bf16*)(ws + (3u << 20));
    float*  xn = (float*) (ws + (4u << 20));
    float*  yn = (float*) (ws + (4u << 20) + (1u << 15));

    prep_kernel<<<(N + M) / 4, 256, 0, stream>>>(x, y, xh, xl, xn, yh, yl, yn);

    dim3 grid(M / 128, N / 128);
    rbf_kernel<<<grid, 256, 0, stream>>>(xh, xl, xn, yh, yl, yn, sig, out);
}

// Round 3
// 270.577 us; speedup vs baseline: 1.1445x; 1.0762x over previous
//
#include <hip/hip_runtime.h>
#include <hip/hip_bf16.h>

#define N 8192
#define M 8192
#define D 64

typedef __bf16 bf16x8 __attribute__((ext_vector_type(8)));
typedef float f32x4 __attribute__((ext_vector_type(4)));

// ---------------------------------------------------------------------------
// Prep: split fp32 rows into bf16 hi/lo + fp32 row norms, AND store hi/lo in
// MFMA-fragment order so the main kernel's loads are fully dense.
//
// Swizzled layout (per 64-row group g, 4096 elements):
//   x (A-operand):  elem(row m=ti*16+l16, K=k*32+quad*8+e) at
//                   g*4096 + ((ti*2+k)*64 + quad*16 + l16)*8 + e
//   y (B-operand, incl. the store-coalescing col permutation col=4*l16+t):
//                   g*4096 + ((t*2+k)*64 + quad*16 + l16)*8 + e,  n=4*l16+t
// Main kernel then loads fragment (slot s) as  base + s*512 + lane*8  ->
// one dense 1 KB global_load_dwordx4 per fragment, no gather.
//
// 8 threads per row (one 8-elem chunk each; chunk c: k=c>>2, quad=c&3).
// ---------------------------------------------------------------------------
__global__ __launch_bounds__(256) void prep_kernel(
    const float* __restrict__ x, const float* __restrict__ y,
    __bf16* __restrict__ xsh, __bf16* __restrict__ xsl, float* __restrict__ xn,
    __bf16* __restrict__ ysh, __bf16* __restrict__ ysl, float* __restrict__ yn)
{
    int t   = threadIdx.x;
    int row = blockIdx.x * 32 + (t >> 3);
    int c   = t & 7;                       // chunk: k = c>>2, quad = c&3

    const float* src;
    __bf16 *ph, *pl;
    float* nrm;
    int r;
    bool isx = row < N;
    if (isx) { src = x; ph = xsh; pl = xsl; nrm = xn; r = row; }
    else     { src = y; ph = ysh; pl = ysl; nrm = yn; r = row - N; }

    const float* p = src + (size_t)r * D + c * 8;
    f32x4 a = *reinterpret_cast<const f32x4*>(p);
    f32x4 b = *reinterpret_cast<const f32x4*>(p + 4);
    float v[8] = {a[0], a[1], a[2], a[3], b[0], b[1], b[2], b[3]};

    bf16x8 hv, lv;
    float s = 0.0f;
    #pragma unroll
    for (int i = 0; i < 8; ++i) {
        float vi = v[i];
        __bf16 hi = (__bf16)vi;            // RNE round to bf16
        float lof = vi - (float)hi;        // exact residual
        hv[i] = hi;
        lv[i] = (__bf16)lof;
        s += vi * vi;
    }
    // reduce norm over the 8 threads of this row (aligned 8-lane groups)
    s += __shfl_down(s, 4);
    s += __shfl_down(s, 2);
    s += __shfl_down(s, 1);

    int g = r >> 6, m = r & 63;
    int slot;
    if (isx) slot = ((m >> 4) * 2 + (c >> 2)) * 64 + (c & 3) * 16 + (m & 15);
    else     slot = ((m & 3)  * 2 + (c >> 2)) * 64 + (c & 3) * 16 + (m >> 2);
    size_t idx = (size_t)g * 4096 + (size_t)slot * 8;

    *reinterpret_cast<bf16x8*>(ph + idx) = hv;
    *reinterpret_cast<bf16x8*>(pl + idx) = lv;
    if (c == 0) nrm[r] = s;
}

// ---------------------------------------------------------------------------
// Main: 128x128 tile per 256-thread block; 64x64 per wave.
// bf16x3 split precision via 16x16x32 MFMA (xh*yh + xh*yl + xl*yh).
// Inputs pre-swizzled -> every fragment load is a dense 1 KB dwordx4.
// Output stored nontemporally (f32x4, cols 4*l16..+3 contiguous) to avoid
// thrashing L2/L3 with the 256 MB write stream.
// C/D: n = lane&15, m = quad*4 + reg  (verified m89/m91); B col = jb+4*l16+t.
// ---------------------------------------------------------------------------
__global__ __launch_bounds__(256) void rbf_kernel(
    const __bf16* __restrict__ xsh, const __bf16* __restrict__ xsl,
    const float* __restrict__ xn,
    const __bf16* __restrict__ ysh, const __bf16* __restrict__ ysl,
    const float* __restrict__ yn,
    const float* __restrict__ sig, float* __restrict__ out)
{
    int tid  = threadIdx.x;
    int wave = tid >> 6;
    int lane = tid & 63;
    int quad = lane >> 4;
    int l16  = lane & 15;

    int i_base = blockIdx.y * 128 + (wave >> 1) * 64;
    int j_base = blockIdx.x * 128 + (wave & 1) * 64;

    float s = sig[0];
    float scale = -0.5f / (s * s);

    // B fragments: dense loads, resident across the ti loop (64 VGPRs).
    const __bf16* pbh = ysh + (size_t)(j_base >> 6) * 4096 + lane * 8;
    const __bf16* pbl = ysl + (size_t)(j_base >> 6) * 4096 + lane * 8;
    bf16x8 Bh[4][2], Bl[4][2];
    #pragma unroll
    for (int t = 0; t < 4; ++t)
        #pragma unroll
        for (int k = 0; k < 2; ++k) {
            Bh[t][k] = *reinterpret_cast<const bf16x8*>(pbh + (t * 2 + k) * 512);
            Bl[t][k] = *reinterpret_cast<const bf16x8*>(pbl + (t * 2 + k) * 512);
        }
    f32x4 ynv = *reinterpret_cast<const f32x4*>(yn + j_base + 4 * l16);

    const __bf16* pah = xsh + (size_t)(i_base >> 6) * 4096 + lane * 8;
    const __bf16* pal = xsl + (size_t)(i_base >> 6) * 4096 + lane * 8;

    #pragma unroll
    for (int ti = 0; ti < 4; ++ti) {
        bf16x8 Ah[2], Al[2];
        #pragma unroll
        for (int k = 0; k < 2; ++k) {
            Ah[k] = *reinterpret_cast<const bf16x8*>(pah + (ti * 2 + k) * 512);
            Al[k] = *reinterpret_cast<const bf16x8*>(pal + (ti * 2 + k) * 512);
        }
        f32x4 xnv = *reinterpret_cast<const f32x4*>(xn + i_base + ti * 16 + quad * 4);

        f32x4 acc[4];
        #pragma unroll
        for (int t = 0; t < 4; ++t) acc[t] = (f32x4){0.f, 0.f, 0.f, 0.f};

        #pragma unroll
        for (int k = 0; k < 2; ++k)
            #pragma unroll
            for (int t = 0; t < 4; ++t) {
                acc[t] = __builtin_amdgcn_mfma_f32_16x16x32_bf16(Ah[k], Bh[t][k], acc[t], 0, 0, 0);
                acc[t] = __builtin_amdgcn_mfma_f32_16x16x32_bf16(Ah[k], Bl[t][k], acc[t], 0, 0, 0);
                acc[t] = __builtin_amdgcn_mfma_f32_16x16x32_bf16(Al[k], Bh[t][k], acc[t], 0, 0, 0);
            }

        // Epilogue: one nontemporal dwordx4 per r (cols 4*l16..+3 contiguous).
        #pragma unroll
        for (int r = 0; r < 4; ++r) {
            int row = i_base + ti * 16 + quad * 4 + r;
            f32x4 v;
            #pragma unroll
            for (int t = 0; t < 4; ++t) {
                float sqd = xnv[r] + ynv[t] - 2.0f * acc[t][r];
                sqd = fmaxf(sqd, 0.0f);
                v[t] = __expf(scale * sqd);
            }
            __builtin_nontemporal_store(
                v, reinterpret_cast<f32x4*>(out + (size_t)row * M + j_base + 4 * l16));
        }
    }
}

extern "C" void kernel_launch(void* const* d_in, const int* in_sizes, int n_in,
                              void* d_out, int out_size, void* d_ws, size_t ws_size,
                              hipStream_t stream) {
    const float* x   = (const float*)d_in[0];
    const float* y   = (const float*)d_in[1];
    const float* sig = (const float*)d_in[2];
    float* out = (float*)d_out;

    char* ws = (char*)d_ws;
    __bf16* xsh = (__bf16*)(ws);
    __bf16* xsl = (__bf16*)(ws + (1u << 20));
    __bf16* ysh = (__bf16*)(ws + (2u << 20));
    __bf16* ysl = (__bf16*)(ws + (3u << 20));
    float*  xn  = (float*) (ws + (4u << 20));
    float*  yn  = (float*) (ws + (4u << 20) + (1u << 15));

    prep_kernel<<<(N + M) / 32, 256, 0, stream>>>(x, y, xsh, xsl, xn, ysh, ysl, yn);

    dim3 grid(M / 128, N / 128);
    rbf_kernel<<<grid, 256, 0, stream>>>(xsh, xsl, xn, ysh, ysl, yn, sig, out);
}